// Round 1
// 1260.255 us; speedup vs baseline: 1.0156x; 1.0156x over previous
//
#include <hip/hip_runtime.h>
#include <math.h>

#define B 512
#define T 500
#define ENC 1024
#define DEC 1024

// ---------------------------------------------------------------------------
// Kernel 1: sub[b,e] = sum_d dec[b,d] * W[e,d]   (C = A * W^T, both K-major)
// M=512 (b), N=1024 (e), K=1024 (d). BM=32, BN=64, BK=16, 256 threads,
// 2x4 microtile per thread. grid (16,16) = 256 blocks -> full CU coverage.
// NEW: global->register prefetch double-buffer (1 wave/SIMD => latency was
// fully exposed per tile; now the next tile's loads fly during compute).
// ---------------------------------------------------------------------------
#define GM 32
#define GN 64
#define GK 16

__global__ __launch_bounds__(256) void gemm_sub(
    const float* __restrict__ A,   // [512,1024] decoderFeature
    const float* __restrict__ Wm,  // [1024,1024] W  (row e, col d)
    float* __restrict__ C)         // [512,1024] sub
{
    __shared__ float As[GK][GM + 2];  // [k][m]
    __shared__ float Bs[GK][GN + 4];  // [k][n]

    const int tid = threadIdx.x;
    const int bm0 = blockIdx.y * GM;
    const int bn0 = blockIdx.x * GN;

    const int tx = tid & 15;
    const int ty = tid >> 4;

    float accr[2][4] = {{0.f,0.f,0.f,0.f},{0.f,0.f,0.f,0.f}};

    const int arow = tid >> 3;          // 0..31
    const int acol = (tid & 7) * 2;     // 0..14
    const int brow = tid >> 2;          // 0..63
    const int bcol = (tid & 3) * 4;     // 0..12

    const float* aptr = A  + (size_t)(bm0 + arow) * DEC + acol;
    const float* bptr = Wm + (size_t)(bn0 + brow) * DEC + bcol;

    float2 a2 = *(const float2*)(aptr);
    float4 b4 = *(const float4*)(bptr);

    for (int k0 = 0; k0 < DEC; k0 += GK) {
        As[acol][arow]     = a2.x;
        As[acol + 1][arow] = a2.y;
        Bs[bcol][brow]     = b4.x;
        Bs[bcol + 1][brow] = b4.y;
        Bs[bcol + 2][brow] = b4.z;
        Bs[bcol + 3][brow] = b4.w;
        __syncthreads();

        // prefetch next tile while this tile computes
        if (k0 + GK < DEC) {
            a2 = *(const float2*)(aptr + k0 + GK);
            b4 = *(const float4*)(bptr + k0 + GK);
        }

#pragma unroll
        for (int k = 0; k < GK; k++) {
            float2 av = *(const float2*)&As[k][ty * 2];
            float4 bv = *(const float4*)&Bs[k][tx * 4];
            accr[0][0] = fmaf(av.x, bv.x, accr[0][0]);
            accr[0][1] = fmaf(av.x, bv.y, accr[0][1]);
            accr[0][2] = fmaf(av.x, bv.z, accr[0][2]);
            accr[0][3] = fmaf(av.x, bv.w, accr[0][3]);
            accr[1][0] = fmaf(av.y, bv.x, accr[1][0]);
            accr[1][1] = fmaf(av.y, bv.y, accr[1][1]);
            accr[1][2] = fmaf(av.y, bv.z, accr[1][2]);
            accr[1][3] = fmaf(av.y, bv.w, accr[1][3]);
        }
        __syncthreads();
    }

    float4 c0 = make_float4(accr[0][0], accr[0][1], accr[0][2], accr[0][3]);
    float4 c1 = make_float4(accr[1][0], accr[1][1], accr[1][2], accr[1][3]);
    *(float4*)(C + (size_t)(bm0 + ty * 2) * ENC + bn0 + tx * 4)     = c0;
    *(float4*)(C + (size_t)(bm0 + ty * 2 + 1) * ENC + bn0 + tx * 4) = c1;
}

// ---------------------------------------------------------------------------
// Kernel 2: fused attention, per-wave online softmax, TWO t-rows per wave
// per iteration (stride 16). Ping-pong prefetch (no register-copy loop).
// enc is read EXACTLY ONCE, only for valid t < len, fully coalesced.
// ---------------------------------------------------------------------------
#define NW 8
#define BLK (NW * 64)

#define LOADROW(E, TT) do {                                            \
    const float* _p = encb + (size_t)(TT) * ENC + 4 * lane;            \
    float4 _v0 = *(const float4*)(_p);                                 \
    float4 _v1 = *(const float4*)(_p + 256);                           \
    float4 _v2 = *(const float4*)(_p + 512);                           \
    float4 _v3 = *(const float4*)(_p + 768);                           \
    E[0]=_v0.x;  E[1]=_v0.y;  E[2]=_v0.z;  E[3]=_v0.w;                 \
    E[4]=_v1.x;  E[5]=_v1.y;  E[6]=_v1.z;  E[7]=_v1.w;                 \
    E[8]=_v2.x;  E[9]=_v2.y;  E[10]=_v2.z; E[11]=_v2.w;                \
    E[12]=_v3.x; E[13]=_v3.y; E[14]=_v3.z; E[15]=_v3.w;                \
} while (0)

#define LOADPAIR(E0, E1, TT) do {                                      \
    LOADROW(E0, TT);                                                   \
    if ((TT) + 1 < len) LOADROW(E1, (TT) + 1);                         \
} while (0)

// process rows (TT, TT+1); E0 always valid, E1 valid iff TT+1 < len
#define PROCESS_PAIR(E0, E1, TT) do {                                  \
    const bool _r1 = ((TT) + 1 < len);                                 \
    if (!_r1) {                                                        \
        _Pragma("unroll")                                              \
        for (int _i = 0; _i < 16; _i++) E1[_i] = 0.f;                  \
    }                                                                  \
    float _d0a = 0.f, _d0b = 0.f, _d1a = 0.f, _d1b = 0.f;              \
    _Pragma("unroll")                                                  \
    for (int _i = 0; _i < 16; _i += 2) {                               \
        _d0a = fmaf(E0[_i],     sub_r[_i],     _d0a);                  \
        _d0b = fmaf(E0[_i + 1], sub_r[_i + 1], _d0b);                  \
        _d1a = fmaf(E1[_i],     sub_r[_i],     _d1a);                  \
        _d1b = fmaf(E1[_i + 1], sub_r[_i + 1], _d1b);                  \
    }                                                                  \
    float _d0 = _d0a + _d0b;                                           \
    float _d1 = _d1a + _d1b;                                           \
    _Pragma("unroll")                                                  \
    for (int _off = 32; _off > 0; _off >>= 1) {                        \
        _d0 += __shfl_xor(_d0, _off, 64);                              \
        _d1 += __shfl_xor(_d1, _off, 64);                              \
    }                                                                  \
    if (lane == 0) {                                                   \
        lds_scores[(TT)] = _d0;                                        \
        if (_r1) lds_scores[(TT) + 1] = _d1;                           \
    }                                                                  \
    const float _d1e = _r1 ? _d1 : -INFINITY;                          \
    const float _md  = fmaxf(_d0, _d1e);                               \
    if (_md > m) {                                                     \
        const float _al = __expf(m - _md);   /* first iter: 0 */       \
        const float _p0 = __expf(_d0 - _md);                           \
        const float _p1 = _r1 ? __expf(_d1 - _md) : 0.f;               \
        l = fmaf(l, _al, _p0 + _p1);                                   \
        _Pragma("unroll")                                              \
        for (int _i = 0; _i < 16; _i++)                                \
            acc[_i] = fmaf(acc[_i], _al,                               \
                           fmaf(_p0, E0[_i], _p1 * E1[_i]));           \
        m = _md;                                                       \
    } else {                                                           \
        const float _p0 = __expf(_d0 - m);                             \
        const float _p1 = _r1 ? __expf(_d1 - m) : 0.f;                 \
        l += _p0 + _p1;                                                \
        _Pragma("unroll")                                              \
        for (int _i = 0; _i < 16; _i++)                                \
            acc[_i] = fmaf(_p1, E1[_i], fmaf(_p0, E0[_i], acc[_i]));   \
    }                                                                  \
} while (0)

__global__ __launch_bounds__(BLK, 4) void attn_fused(
    const float* __restrict__ sub,   // [B, ENC]
    const float* __restrict__ enc,   // [B, T, ENC]
    const int* __restrict__ lens,    // [B]
    float* __restrict__ out_attn,    // [B, T]
    float* __restrict__ out_sum)     // [B, ENC]
{
    __shared__ float lds_scores[T];
    __shared__ float lds_m[NW];
    __shared__ float lds_l[NW];
    __shared__ float lds_o[NW][ENC];

    const int b    = blockIdx.x;
    const int tid  = threadIdx.x;
    const int wave = tid >> 6;
    const int lane = tid & 63;
    const int len  = lens[b];

    const float* encb = enc + (size_t)b * T * ENC;
    const float* subb = sub + (size_t)b * ENC;

    float sub_r[16];
#pragma unroll
    for (int c = 0; c < 4; c++) {
        float4 s4 = *(const float4*)(subb + c * 256 + 4 * lane);
        sub_r[c * 4 + 0] = s4.x; sub_r[c * 4 + 1] = s4.y;
        sub_r[c * 4 + 2] = s4.z; sub_r[c * 4 + 3] = s4.w;
    }

    float acc[16];
#pragma unroll
    for (int i = 0; i < 16; i++) acc[i] = 0.f;
    float m = -INFINITY;
    float l = 0.f;

    // wave w owns row pairs starting at t = 2w, stride 2*NW = 16.
    int t = 2 * wave;
    if (t < len) {
        float eA0[16], eA1[16], eB0[16], eB1[16];
        LOADPAIR(eA0, eA1, t);
        for (;;) {
            const int tB = t + 2 * NW;
            const bool vB = (tB < len);
            if (vB) LOADPAIR(eB0, eB1, tB);
            PROCESS_PAIR(eA0, eA1, t);
            if (!vB) break;
            const int tA = tB + 2 * NW;
            const bool vA = (tA < len);
            if (vA) LOADPAIR(eA0, eA1, tA);
            PROCESS_PAIR(eB0, eB1, tB);
            if (!vA) break;
            t = tA;
        }
    }

    if (lane == 0) { lds_m[wave] = m; lds_l[wave] = l; }
#pragma unroll
    for (int c = 0; c < 4; c++) {
        float4 v = make_float4(acc[c * 4 + 0], acc[c * 4 + 1],
                               acc[c * 4 + 2], acc[c * 4 + 3]);
        *(float4*)&lds_o[wave][c * 256 + 4 * lane] = v;
    }
    __syncthreads();

    // combine 8 per-wave online-softmax states (every thread, redundantly)
    float mg = -INFINITY;
#pragma unroll
    for (int w = 0; w < NW; w++) mg = fmaxf(mg, lds_m[w]);
    float scale[NW];
    float lg = 0.f;
#pragma unroll
    for (int w = 0; w < NW; w++) {
        float mw = lds_m[w];
        float s  = (mw == -INFINITY) ? 0.f : __expf(mw - mg);
        scale[w] = s;
        lg = fmaf(lds_l[w], s, lg);
    }
    const float inv_l = 1.f / lg;   // len >= 1 guarantees lg > 0

    // sumResult: 2 elements per thread (1024 / 512)
    const int e0 = 2 * tid;
    float o0 = 0.f, o1 = 0.f;
#pragma unroll
    for (int w = 0; w < NW; w++) {
        o0 = fmaf(scale[w], lds_o[w][e0], o0);
        o1 = fmaf(scale[w], lds_o[w][e0 + 1], o1);
    }
    *(float2*)(out_sum + (size_t)b * ENC + e0) = make_float2(o0 * inv_l, o1 * inv_l);

    // attn probabilities (zeros for masked t)
    for (int tt = tid; tt < T; tt += BLK) {
        float v = 0.f;
        if (tt < len) v = __expf(lds_scores[tt] - mg) * inv_l;
        out_attn[(size_t)b * T + tt] = v;
    }
}

// ---------------------------------------------------------------------------
extern "C" void kernel_launch(void* const* d_in, const int* in_sizes, int n_in,
                              void* d_out, int out_size, void* d_ws, size_t ws_size,
                              hipStream_t stream) {
    const float* dec  = (const float*)d_in[0];   // [512,1024]
    const float* enc  = (const float*)d_in[1];   // [512,500,1024]
    const int*   lens = (const int*)d_in[2];     // [512]
    const float* Wm   = (const float*)d_in[3];   // [1024,1024]

    float* out       = (float*)d_out;
    float* out_attn  = out;                       // 512*500
    float* out_sum   = out + (size_t)B * T;       // 512*1024
    float* sub       = (float*)d_ws;              // 512*1024 floats = 2 MB scratch

    gemm_sub<<<dim3(16, 16), 256, 0, stream>>>(dec, Wm, sub);
    attn_fused<<<dim3(B), BLK, 0, stream>>>(sub, enc, lens, out_attn, out_sum);
}